// Round 19
// baseline (1396.546 us; speedup 1.0000x reference)
//
#include <hip/hip_runtime.h>
#include <hip/hip_bf16.h>
#include <math.h>

static constexpr int Bn = 8192;
static constexpr int Hn = 16384;
static constexpr int Dn = 1536;
static constexpr int KTOP = 64;
static constexpr int KE = 1536;             // single-pass bf16 GEMM K
static constexpr int WSTR = 2048;           // padded W_decT row stride (bf16)
static constexpr double EPSD = 1e-5;

// ---- workspace byte offsets (peak ~444 MB; >=672 MB proven mapped, r1/r2) ----
static constexpr size_t MU_OFF  = 0;                 // float[8192]
static constexpr size_t STD_OFF = 32768;             // float[8192]
static constexpr size_t CNT_OFF = 98304;             // unsigned[8192]
static constexpr size_t NNZ_OFF = 131072;            // unsigned[1]
static constexpr size_t SUM_OFF = 131200;            // double[2]
static constexpr size_t MUD_OFF = 262144;            // double[8192]
static constexpr size_t RID_OFF = 327680;            // double[8192]
static constexpr size_t IDX_OFF = (size_t)1 << 20;   // int[8192*128]
static constexpr size_t VAL_OFF = (size_t)6 << 20;   // float[8192*128]
static constexpr size_t AP_OFF  = (size_t)16 << 20;  // bf16[8192*1536]   (25 MB)
static constexpr size_t BP_OFF  = (size_t)48 << 20;  // bf16[16384*1536]  (50 MB)
static constexpr size_t WT_OFF  = (size_t)104 << 20; // bf16[16384*2048]  (64 MB)
static constexpr size_t H16_OFF = (size_t)176 << 20; // bf16[8192*16384] (268 MB)

typedef __attribute__((ext_vector_type(8))) short short8;
typedef __attribute__((ext_vector_type(4))) float f32x4;

static __device__ __forceinline__ unsigned short f2bf(float f) {
    __hip_bfloat16 b = __float2bfloat16(f);
    return *reinterpret_cast<unsigned short*>(&b);
}
static __device__ __forceinline__ float bf2f(unsigned short u) {
    return __uint_as_float(((unsigned)u) << 16);
}
static __device__ __forceinline__ void gload_lds16(const void* g, void* l) {
    __builtin_amdgcn_global_load_lds(
        (const __attribute__((address_space(1))) unsigned int*)g,
        (__attribute__((address_space(3))) unsigned int*)l, 16, 0, 0);
}

__global__ void k_zero(unsigned* nnz, double* sums) {
    if (threadIdx.x == 0) { *nnz = 0u; sums[0] = 0.0; sums[1] = 0.0; }
}

// f64 row stats + write bf16 A row (xn - pre_bias) in one pass
__global__ __launch_bounds__(256) void k_rowstats(const float* __restrict__ x,
                                                  const float* __restrict__ pre_bias,
                                                  double* __restrict__ muD,
                                                  double* __restrict__ rinvD,
                                                  float* __restrict__ muF,
                                                  float* __restrict__ stdF,
                                                  unsigned short* __restrict__ Ap) {
    const int row = blockIdx.x;
    const int tid = threadIdx.x;
    const float* xr = x + (size_t)row * Dn;
    float v[6];
#pragma unroll
    for (int i = 0; i < 6; ++i) v[i] = xr[tid + 256 * i];
    double s = 0.0;
#pragma unroll
    for (int i = 0; i < 6; ++i) s += (double)v[i];
    __shared__ double redD[4];
    __shared__ double smu, srin;
#pragma unroll
    for (int o = 32; o > 0; o >>= 1) s += __shfl_down(s, o);
    if ((tid & 63) == 0) redD[tid >> 6] = s;
    __syncthreads();
    if (tid == 0) smu = (redD[0] + redD[1] + redD[2] + redD[3]) / (double)Dn;
    __syncthreads();
    const double m = smu;
    double q = 0.0;
#pragma unroll
    for (int i = 0; i < 6; ++i) { double d = (double)v[i] - m; q += d * d; }
#pragma unroll
    for (int o = 32; o > 0; o >>= 1) q += __shfl_down(q, o);
    if ((tid & 63) == 0) redD[tid >> 6] = q;
    __syncthreads();
    if (tid == 0) {
        double var = (redD[0] + redD[1] + redD[2] + redD[3]) / (double)(Dn - 1);
        double sd = sqrt(var);
        muD[row] = m;
        srin = 1.0 / (sd + EPSD);
        rinvD[row] = srin;
        muF[row] = (float)m;
        stdF[row] = (float)sd;
    }
    __syncthreads();
    const double ri = srin;
    unsigned short* ar = Ap + (size_t)row * KE;
#pragma unroll
    for (int i = 0; i < 6; ++i) {
        const int d = tid + i * 256;
        double a = ((double)v[i] - m) * ri - (double)pre_bias[d];
        ar[d] = f2bf((float)a);
    }
}

// Wenc f32 -> bf16
__global__ __launch_bounds__(256) void k_splitW(const float* __restrict__ Wenc,
                                                unsigned short* __restrict__ Bp) {
    const int row = blockIdx.x;
    const int tid = threadIdx.x;
    const float2* wr = (const float2*)(Wenc + (size_t)row * Dn);
    ushort2* br = (ushort2*)(Bp + (size_t)row * KE);
#pragma unroll
    for (int i = 0; i < 3; ++i) {
        float2 w = wr[tid + i * 256];
        ushort2 o; o.x = f2bf(w.x); o.y = f2bf(w.y);
        br[tid + i * 256] = o;
    }
}

// W_dec (D,H) f32 -> W_decT (H, stride WSTR) bf16 in ws; pads never read
__global__ __launch_bounds__(256) void k_transpose(const float* __restrict__ Wdec,
                                                   unsigned short* __restrict__ WdecT) {
    __shared__ float tile[32][33];
    const int h0 = blockIdx.x * 32;
    const int d0 = blockIdx.y * 32;
    const int tx = threadIdx.x & 31;
    const int ty = threadIdx.x >> 5;
#pragma unroll
    for (int r = 0; r < 4; ++r) {
        int d = ty + r * 8;
        tile[d][tx] = Wdec[(size_t)(d0 + d) * Hn + h0 + tx];
    }
    __syncthreads();
#pragma unroll
    for (int r = 0; r < 4; ++r) {
        int h = ty + r * 8;
        WdecT[(size_t)(h0 + h) * WSTR + d0 + tx] = f2bf(tile[tx][h]);
    }
}

// bf16 MFMA GEMM: 256x256 tile, BK=64, 8 waves, counted-vmcnt pipeline
// (round-12 verified)
__global__ __launch_bounds__(512, 2) void k_gemm(const unsigned short* __restrict__ Ap,
                                                 const unsigned short* __restrict__ Bp,
                                                 const float* __restrict__ lat_bias,
                                                 unsigned short* __restrict__ hout16) {
    __shared__ unsigned short AsBuf[2][256 * 64];
    __shared__ unsigned short BsBuf[2][256 * 64];
    const int tid = threadIdx.x;
    const int lane = tid & 63;
    const int w = tid >> 6;
    const int wm = w >> 2;
    const int wn = w & 3;

    const int nwg = (Bn / 256) * (Hn / 256);          // 2048, %8 == 0
    int swz = (blockIdx.x % 8) * (nwg / 8) + blockIdx.x / 8;
    int st = swz >> 6;
    int wi = swz & 63;
    int stm = st >> 3, stn = st & 7;
    const int bm = stm * 8 + (wi >> 3);
    const int bn = stn * 8 + (wi & 7);

    const size_t arow0 = (size_t)(bm * 256) * KE;
    const size_t brow0 = (size_t)(bn * 256) * KE;

    #define STAGE_TILE(kt, buf)                                                   \
        {                                                                         \
            _Pragma("unroll")                                                     \
            for (int l = 0; l < 4; ++l) {                                         \
                const int idx = l * 512 + tid;                                    \
                const int row = idx >> 3, slot = idx & 7;                         \
                const int ssl = slot ^ (row & 7);                                 \
                gload_lds16(Ap + arow0 + (size_t)row * KE + (kt) * 64 + ssl * 8,  \
                            (char*)AsBuf[buf] + idx * 16);                        \
                gload_lds16(Bp + brow0 + (size_t)row * KE + (kt) * 64 + ssl * 8,  \
                            (char*)BsBuf[buf] + idx * 16);                        \
            }                                                                     \
        }

    f32x4 acc[8][4];
#pragma unroll
    for (int i = 0; i < 8; ++i)
#pragma unroll
        for (int j = 0; j < 4; ++j) acc[i][j] = (f32x4){0.f, 0.f, 0.f, 0.f};

    constexpr int NT = KE / 64;       // 24
    STAGE_TILE(0, 0);
    STAGE_TILE(1, 1);
    asm volatile("s_waitcnt vmcnt(8)" ::: "memory");
    __builtin_amdgcn_s_barrier();
    asm volatile("" ::: "memory");

    for (int t = 0; t < NT; ++t) {
        const int buf = t & 1;
        const unsigned short* Ab = AsBuf[buf];
        const unsigned short* Bb = BsBuf[buf];
        short8 bfr[4][2];
#pragma unroll
        for (int fj = 0; fj < 4; ++fj)
#pragma unroll
            for (int kk = 0; kk < 2; ++kk) {
                const int br = wn * 64 + fj * 16 + (lane & 15);
                const int slot = (kk * 4 + (lane >> 4)) ^ (br & 7);
                bfr[fj][kk] = *(const short8*)((const char*)Bb + br * 128 + slot * 16);
            }
#pragma unroll
        for (int qm = 0; qm < 2; ++qm) {
            short8 afr[4][2];
#pragma unroll
            for (int fi = 0; fi < 4; ++fi)
#pragma unroll
                for (int kk = 0; kk < 2; ++kk) {
                    const int ar = wm * 128 + qm * 64 + fi * 16 + (lane & 15);
                    const int slot = (kk * 4 + (lane >> 4)) ^ (ar & 7);
                    afr[fi][kk] = *(const short8*)((const char*)Ab + ar * 128 + slot * 16);
                }
#pragma unroll
            for (int kk = 0; kk < 2; ++kk)
#pragma unroll
                for (int fi = 0; fi < 4; ++fi)
#pragma unroll
                    for (int fj = 0; fj < 4; ++fj)
                        acc[qm * 4 + fi][fj] = __builtin_amdgcn_mfma_f32_16x16x32_bf16(
                            afr[fi][kk], bfr[fj][kk], acc[qm * 4 + fi][fj], 0, 0, 0);
        }
        __builtin_amdgcn_s_barrier();
        asm volatile("" ::: "memory");
        if (t + 2 < NT) {
            STAGE_TILE(t + 2, buf);
            asm volatile("s_waitcnt vmcnt(8)" ::: "memory");
        } else {
            asm volatile("s_waitcnt vmcnt(0)" ::: "memory");
        }
        __builtin_amdgcn_s_barrier();
        asm volatile("" ::: "memory");
    }
    #undef STAGE_TILE

    const int col = lane & 15;
#pragma unroll
    for (int fj = 0; fj < 4; ++fj) {
        const int gn = bn * 256 + wn * 64 + fj * 16 + col;
        const float bias = lat_bias[gn];
#pragma unroll
        for (int fi8 = 0; fi8 < 8; ++fi8) {
            const int gm0 = bm * 256 + wm * 128 + fi8 * 16 + (lane >> 4) * 4;
#pragma unroll
            for (int r = 0; r < 4; ++r) {
                float vv = acc[fi8][fj][r] + bias;
                hout16[(size_t)(gm0 + r) * Hn + gn] = f2bf(fmaxf(vv, 0.f));
            }
        }
    }
}

// FUSED topsel — r16/r18 structure with TERNARY bisection: two midpoints per
// scan, counts packed into one int ((c1<<16)|c2, counts<65536) so the
// reduce/shared/barrier pattern is identical. 10 scans instead of 15;
// identical exact 64th-largest key (invariant-preserving 3-way split).
__global__ __launch_bounds__(256) void k_topsel(const unsigned short* __restrict__ h16,
                                                const float* __restrict__ x,
                                                const float* __restrict__ Wenc,
                                                const float* __restrict__ pre_bias,
                                                const float* __restrict__ lat_bias,
                                                const double* __restrict__ muD,
                                                const double* __restrict__ rinvD,
                                                unsigned* __restrict__ counts,
                                                int* __restrict__ idx_list,
                                                float* __restrict__ val_list) {
    const int row = blockIdx.x;
    const int tid = threadIdx.x;
    const int lane = tid & 63;
    const int wid = tid >> 6;
    const unsigned short* hr16 = h16 + (size_t)row * Hn;
    const unsigned* hu = (const unsigned*)hr16;
    unsigned u[32];
#pragma unroll
    for (int j = 0; j < 32; ++j) u[j] = hu[j * 256 + tid];

    // exact 64th-largest bf16 key, ternary bisection (atomic-free)
    // invariant: count(>=lo) >= K and count(>=hi+1) < K
    __shared__ int wsum[4];
    __shared__ unsigned sbc;
    unsigned lo = 0, hi = 0x7FFFu;    // keys <= 0x7F7F (ReLU, finite)
    while (lo < hi) {
        const unsigned span = hi - lo;
        const unsigned m1 = lo + 1 + (span - 1) / 3;
        const unsigned m2 = lo + 1 + (2 * (span - 1)) / 3;
        int c = 0;   // (count>=m1)<<16 | (count>=m2)
#pragma unroll
        for (int j = 0; j < 32; ++j) {
            const unsigned k0 = u[j] & 0xFFFFu, k1 = u[j] >> 16;
            c += ((k0 >= m1) ? 0x10000 : 0) + ((k0 >= m2) ? 1 : 0);
            c += ((k1 >= m1) ? 0x10000 : 0) + ((k1 >= m2) ? 1 : 0);
        }
#pragma unroll
        for (int o = 32; o > 0; o >>= 1) c += __shfl_down(c, o);
        if ((tid & 63) == 0) wsum[tid >> 6] = c;
        __syncthreads();
        if (tid == 0) sbc = (unsigned)(wsum[0] + wsum[1] + wsum[2] + wsum[3]);
        __syncthreads();
        const unsigned c1 = sbc >> 16, c2 = sbc & 0xFFFFu;
        if (c2 >= (unsigned)KTOP)      { lo = m2; }
        else if (c1 >= (unsigned)KTOP) { lo = m1; hi = m2 - 1; }
        else                           { hi = m1 - 1; }
        __syncthreads();
    }
    const float thr = bf2f((unsigned short)lo);
    const float DELTA = 0.02f;
    const float hi_t = thr + DELTA;
    const float lo_t = thr - DELTA;

    // classify from registers
    constexpr int MAXC = 128;
    __shared__ int s_g, s_c;
    __shared__ int cidx[MAXC];
    __shared__ double cvalD[MAXC];
    __shared__ float cref[MAXC];
    __shared__ unsigned char csel[MAXC];
    __shared__ unsigned long long kmask[256];
    __shared__ unsigned ccnt[256];
    __shared__ unsigned cinc[256];
    if (tid == 0) { s_g = 0; s_c = 0; }
    __syncthreads();
    int g_loc = 0;
#pragma unroll
    for (int j = 0; j < 32; ++j) {
        float v0 = bf2f((unsigned short)(u[j] & 0xFFFFu));
        float v1 = bf2f((unsigned short)(u[j] >> 16));
        const int i0 = 2 * (j * 256 + tid);
        if (v0 > hi_t) g_loc++;
        else if (v0 >= lo_t) {
            int p = atomicAdd(&s_c, 1);
            if (p < MAXC) cidx[p] = i0;
        }
        if (v1 > hi_t) g_loc++;
        else if (v1 >= lo_t) {
            int p = atomicAdd(&s_c, 1);
            if (p < MAXC) cidx[p] = i0 + 1;
        }
    }
    if (g_loc) atomicAdd(&s_g, g_loc);
    __syncthreads();
    const int ec = (s_c < MAXC) ? s_c : MAXC;

    // exact f64 recompute of band candidates, wave-parallel
    {
        const double rmu = muD[row];
        const double rin = rinvD[row];
        const float* xr = x + (size_t)row * Dn;
        for (int e = wid; e < ec; e += 4) {
            const int feat = cidx[e];
            const float* wr = Wenc + (size_t)feat * Dn;
            double acc = 0.0;
            for (int d = lane; d < Dn; d += 64) {
                double xn = ((double)xr[d] - rmu) * rin - (double)pre_bias[d];
                acc = fma(xn, (double)wr[d], acc);
            }
#pragma unroll
            for (int o = 32; o > 0; o >>= 1) acc += __shfl_down(acc, o);
            if (lane == 0) {
                double hv = acc + (double)lat_bias[feat];
                cvalD[e] = hv;
                float hf = (float)hv;
                cref[e] = hf > 0.f ? hf : 0.f;
            }
        }
    }
    __syncthreads();
    if (tid == 0) {
        const int need = KTOP - s_g;
        for (int e = 0; e < ec; ++e) csel[e] = 0;
        for (int it = 0; it < need && it < ec; ++it) {
            int best = -1; double bv = -1e300; int bidx = 1 << 30;
            for (int e = 0; e < ec; ++e) {
                if (csel[e]) continue;
                if (cvalD[e] > bv || (cvalD[e] == bv && cidx[e] < bidx)) {
                    bv = cvalD[e]; best = e; bidx = cidx[e];
                }
            }
            if (best >= 0) csel[best] = 1;
        }
    }
    __syncthreads();

    // Phase A: per-chunk keep masks (re-read, L2-hot)
    for (int i = 0; i < 64; ++i) {
        const int c = wid * 64 + i;
        const int f = c * 64 + lane;
        float val = bf2f(hr16[f]);
        bool keep;
        if (val > hi_t) keep = true;
        else if (val >= lo_t) {
            keep = false;
            for (int e = 0; e < ec; ++e)
                if (cidx[e] == f) { keep = (csel[e] != 0); break; }
        } else keep = false;
        unsigned long long bm = __ballot(keep);
        if (lane == 0) { kmask[c] = bm; ccnt[c] = (unsigned)__popcll(bm); }
    }
    __syncthreads();
    // Phase B: inclusive prefix over chunk counts
    cinc[tid] = ccnt[tid];
    __syncthreads();
#pragma unroll
    for (int o = 1; o < 256; o <<= 1) {
        unsigned t = cinc[tid] + ((tid >= o) ? cinc[tid - o] : 0u);
        __syncthreads();
        cinc[tid] = t;
        __syncthreads();
    }
    if (tid == 0) {
        unsigned tot = cinc[255];
        counts[row] = tot < 128u ? tot : 128u;
    }
    __syncthreads();
    // Phase C: masked writes
    for (int i = 0; i < 64; ++i) {
        const int c = wid * 64 + i;
        unsigned long long bm = kmask[c];
        if (!bm) continue;
        bool keep = (bm >> lane) & 1ull;
        if (keep) {
            unsigned pos = (cinc[c] - ccnt[c]) +
                           (unsigned)__popcll(bm & ((1ull << lane) - 1ull));
            if (pos < 128u) {
                const int f = c * 64 + lane;
                float sv = bf2f(hr16[f]);
                if (sv >= lo_t && sv <= hi_t) {
                    for (int e = 0; e < ec; ++e)
                        if (cidx[e] == f) { sv = cref[e]; break; }
                }
                idx_list[(size_t)row * 128 + pos] = f;
                val_list[(size_t)row * 128 + pos] = sv;
            }
        }
    }
}

// FUSED hwrite + decoder (round-13 verified)
__global__ __launch_bounds__(256) void k_hwdec(const unsigned* __restrict__ counts,
                                               const int* __restrict__ idx_list,
                                               const float* __restrict__ val_list,
                                               const unsigned short* __restrict__ WdecT,
                                               const float* __restrict__ pre_bias,
                                               const float* __restrict__ muF,
                                               const float* __restrict__ stdF,
                                               float* __restrict__ outh,
                                               float* __restrict__ outr,
                                               unsigned* __restrict__ nnz_acc,
                                               double* __restrict__ sums) {
    const int row = blockIdx.x;
    const int tid = threadIdx.x;
    const unsigned cnt = counts[row];
    __shared__ int sidx[128];
    __shared__ float sval[128];
    if (tid < (int)cnt) {
        sidx[tid] = idx_list[(size_t)row * 128 + tid];
        sval[tid] = val_list[(size_t)row * 128 + tid];
    }
    float* orow = outh + (size_t)row * Hn;
    float4* orow16 = (float4*)orow;
    const float4 z = {0.f, 0.f, 0.f, 0.f};
#pragma unroll
    for (int i = 0; i < 16; ++i) orow16[tid + i * 256] = z;
    __syncthreads();
    float val = 0.f;
    if (tid < (int)cnt) { orow[sidx[tid]] = sval[tid]; val = sval[tid]; }
    float s1 = val, s2 = val * val;
    __shared__ float r1[4], r2[4];
#pragma unroll
    for (int o = 32; o > 0; o >>= 1) {
        s1 += __shfl_down(s1, o);
        s2 += __shfl_down(s2, o);
    }
    if ((tid & 63) == 0) { r1[tid >> 6] = s1; r2[tid >> 6] = s2; }
    __syncthreads();
    if (tid == 0) {
        atomicAdd(sums + 0, (double)(r1[0] + r1[1] + r1[2] + r1[3]));
        atomicAdd(sums + 1, (double)(r2[0] + r2[1] + r2[2] + r2[3]));
        atomicAdd(nnz_acc, cnt);
    }
    if (tid >= 192) return;
    float a[8] = {0.f, 0.f, 0.f, 0.f, 0.f, 0.f, 0.f, 0.f};
    float b[8] = {0.f, 0.f, 0.f, 0.f, 0.f, 0.f, 0.f, 0.f};
    const size_t toff = (size_t)tid * 8;
    unsigned j = 0;
    for (; j + 2 <= cnt; j += 2) {
        short8 w0 = *(const short8*)(WdecT + (size_t)sidx[j] * WSTR + toff);
        short8 w1 = *(const short8*)(WdecT + (size_t)sidx[j + 1] * WSTR + toff);
        const float v0 = sval[j], v1 = sval[j + 1];
#pragma unroll
        for (int i = 0; i < 8; ++i) {
            a[i] = fmaf(v0, bf2f((unsigned short)w0[i]), a[i]);
            b[i] = fmaf(v1, bf2f((unsigned short)w1[i]), b[i]);
        }
    }
    if (j < cnt) {
        short8 w0 = *(const short8*)(WdecT + (size_t)sidx[j] * WSTR + toff);
        const float v0 = sval[j];
#pragma unroll
        for (int i = 0; i < 8; ++i)
            a[i] = fmaf(v0, bf2f((unsigned short)w0[i]), a[i]);
    }
    const float m_ = muF[row], s_ = stdF[row];
    const int d0 = tid * 8;
    float o[8];
#pragma unroll
    for (int i = 0; i < 8; ++i)
        o[i] = ((a[i] + b[i]) + pre_bias[d0 + i]) * s_ + m_;
    float* rrow = outr + (size_t)row * Dn + d0;
    *(float4*)(rrow)     = *(float4*)&o[0];
    *(float4*)(rrow + 4) = *(float4*)&o[4];
}

__global__ void k_final(const unsigned* __restrict__ nnz,
                        const double* __restrict__ sums,
                        float* __restrict__ out3) {
    if (threadIdx.x == 0) {
        const double N = (double)Bn * (double)Hn;
        const double nz = (double)(*nnz);
        const double sparsity = (N - nz) / N;
        const double mean = sums[0] / N;
        double var = (sums[1] - N * mean * mean) / (N - 1.0);
        if (var < 0.0) var = 0.0;
        out3[0] = (float)sparsity;
        out3[1] = (float)mean;
        out3[2] = (float)sqrt(var);
    }
}

extern "C" void kernel_launch(void* const* d_in, const int* in_sizes, int n_in,
                              void* d_out, int out_size, void* d_ws, size_t ws_size,
                              hipStream_t stream) {
    const float* x        = (const float*)d_in[0];
    const float* Wenc     = (const float*)d_in[1];
    const float* Wdec     = (const float*)d_in[2];
    const float* pre_bias = (const float*)d_in[3];
    const float* lat_bias = (const float*)d_in[4];

    char* ws = (char*)d_ws;
    float*          muF    = (float*)(ws + MU_OFF);
    float*          stdF   = (float*)(ws + STD_OFF);
    unsigned*       counts = (unsigned*)(ws + CNT_OFF);
    unsigned*       nnz    = (unsigned*)(ws + NNZ_OFF);
    double*         sums   = (double*)(ws + SUM_OFF);
    double*         muD    = (double*)(ws + MUD_OFF);
    double*         rinvD  = (double*)(ws + RID_OFF);
    int*            idxl   = (int*)(ws + IDX_OFF);
    float*          vall   = (float*)(ws + VAL_OFF);
    unsigned short* Ap     = (unsigned short*)(ws + AP_OFF);
    unsigned short* Bp     = (unsigned short*)(ws + BP_OFF);
    unsigned short* WdecT  = (unsigned short*)(ws + WT_OFF);
    unsigned short* h16    = (unsigned short*)(ws + H16_OFF);

    float* out       = (float*)d_out;
    float* out_recon = out;
    float* out_h     = out + (size_t)Bn * Dn;
    float* out_sc    = out + (size_t)Bn * Dn + (size_t)Bn * Hn;

    hipLaunchKernelGGL(k_zero, dim3(1), dim3(64), 0, stream, nnz, sums);
    hipLaunchKernelGGL(k_rowstats, dim3(Bn), dim3(256), 0, stream,
                       x, pre_bias, muD, rinvD, muF, stdF, Ap);
    hipLaunchKernelGGL(k_splitW, dim3(Hn), dim3(256), 0, stream, Wenc, Bp);
    hipLaunchKernelGGL(k_transpose, dim3(Hn / 32, Dn / 32), dim3(256), 0, stream, Wdec, WdecT);
    hipLaunchKernelGGL(k_gemm, dim3((Bn / 256) * (Hn / 256)), dim3(512), 0, stream,
                       Ap, Bp, lat_bias, h16);
    hipLaunchKernelGGL(k_topsel, dim3(Bn), dim3(256), 0, stream,
                       h16, x, Wenc, pre_bias, lat_bias, muD, rinvD,
                       counts, idxl, vall);
    hipLaunchKernelGGL(k_hwdec, dim3(Bn), dim3(256), 0, stream,
                       counts, idxl, vall, WdecT, pre_bias, muF, stdF,
                       out_h, out_recon, nnz, sums);
    hipLaunchKernelGGL(k_final, dim3(1), dim3(64), 0, stream, nnz, sums, out_sc);
}

// Round 20
// 1368.557 us; speedup vs baseline: 1.0205x; 1.0205x over previous
//
#include <hip/hip_runtime.h>
#include <hip/hip_bf16.h>
#include <math.h>

static constexpr int Bn = 8192;
static constexpr int Hn = 16384;
static constexpr int Dn = 1536;
static constexpr int KTOP = 64;
static constexpr int KE = 1536;             // single-pass bf16 GEMM K
static constexpr int WSTR = 2048;           // padded W_decT row stride (bf16)
static constexpr double EPSD = 1e-5;

// ---- workspace byte offsets (peak ~444 MB; >=672 MB proven mapped, r1/r2) ----
static constexpr size_t MU_OFF  = 0;                 // float[8192]
static constexpr size_t STD_OFF = 32768;             // float[8192]
static constexpr size_t CNT_OFF = 98304;             // unsigned[8192]
static constexpr size_t NNZ_OFF = 131072;            // unsigned[1]
static constexpr size_t SUM_OFF = 131200;            // double[2]
static constexpr size_t MUD_OFF = 262144;            // double[8192]
static constexpr size_t RID_OFF = 327680;            // double[8192]
static constexpr size_t IDX_OFF = (size_t)1 << 20;   // int[8192*128]
static constexpr size_t VAL_OFF = (size_t)6 << 20;   // float[8192*128]
static constexpr size_t AP_OFF  = (size_t)16 << 20;  // bf16[8192*1536]   (25 MB)
static constexpr size_t BP_OFF  = (size_t)48 << 20;  // bf16[16384*1536]  (50 MB)
static constexpr size_t WT_OFF  = (size_t)104 << 20; // bf16[16384*2048]  (64 MB)
static constexpr size_t H16_OFF = (size_t)176 << 20; // bf16[8192*16384] (268 MB)

typedef __attribute__((ext_vector_type(8))) short short8;
typedef __attribute__((ext_vector_type(4))) float f32x4;

static __device__ __forceinline__ unsigned short f2bf(float f) {
    __hip_bfloat16 b = __float2bfloat16(f);
    return *reinterpret_cast<unsigned short*>(&b);
}
static __device__ __forceinline__ float bf2f(unsigned short u) {
    return __uint_as_float(((unsigned)u) << 16);
}
static __device__ __forceinline__ void gload_lds16(const void* g, void* l) {
    __builtin_amdgcn_global_load_lds(
        (const __attribute__((address_space(1))) unsigned int*)g,
        (__attribute__((address_space(3))) unsigned int*)l, 16, 0, 0);
}

__global__ void k_zero(unsigned* nnz, double* sums) {
    if (threadIdx.x == 0) { *nnz = 0u; sums[0] = 0.0; sums[1] = 0.0; }
}

// f64 row stats + write bf16 A row (xn - pre_bias) in one pass
__global__ __launch_bounds__(256) void k_rowstats(const float* __restrict__ x,
                                                  const float* __restrict__ pre_bias,
                                                  double* __restrict__ muD,
                                                  double* __restrict__ rinvD,
                                                  float* __restrict__ muF,
                                                  float* __restrict__ stdF,
                                                  unsigned short* __restrict__ Ap) {
    const int row = blockIdx.x;
    const int tid = threadIdx.x;
    const float* xr = x + (size_t)row * Dn;
    float v[6];
#pragma unroll
    for (int i = 0; i < 6; ++i) v[i] = xr[tid + 256 * i];
    double s = 0.0;
#pragma unroll
    for (int i = 0; i < 6; ++i) s += (double)v[i];
    __shared__ double redD[4];
    __shared__ double smu, srin;
#pragma unroll
    for (int o = 32; o > 0; o >>= 1) s += __shfl_down(s, o);
    if ((tid & 63) == 0) redD[tid >> 6] = s;
    __syncthreads();
    if (tid == 0) smu = (redD[0] + redD[1] + redD[2] + redD[3]) / (double)Dn;
    __syncthreads();
    const double m = smu;
    double q = 0.0;
#pragma unroll
    for (int i = 0; i < 6; ++i) { double d = (double)v[i] - m; q += d * d; }
#pragma unroll
    for (int o = 32; o > 0; o >>= 1) q += __shfl_down(q, o);
    if ((tid & 63) == 0) redD[tid >> 6] = q;
    __syncthreads();
    if (tid == 0) {
        double var = (redD[0] + redD[1] + redD[2] + redD[3]) / (double)(Dn - 1);
        double sd = sqrt(var);
        muD[row] = m;
        srin = 1.0 / (sd + EPSD);
        rinvD[row] = srin;
        muF[row] = (float)m;
        stdF[row] = (float)sd;
    }
    __syncthreads();
    const double ri = srin;
    unsigned short* ar = Ap + (size_t)row * KE;
#pragma unroll
    for (int i = 0; i < 6; ++i) {
        const int d = tid + i * 256;
        double a = ((double)v[i] - m) * ri - (double)pre_bias[d];
        ar[d] = f2bf((float)a);
    }
}

// Wenc f32 -> bf16
__global__ __launch_bounds__(256) void k_splitW(const float* __restrict__ Wenc,
                                                unsigned short* __restrict__ Bp) {
    const int row = blockIdx.x;
    const int tid = threadIdx.x;
    const float2* wr = (const float2*)(Wenc + (size_t)row * Dn);
    ushort2* br = (ushort2*)(Bp + (size_t)row * KE);
#pragma unroll
    for (int i = 0; i < 3; ++i) {
        float2 w = wr[tid + i * 256];
        ushort2 o; o.x = f2bf(w.x); o.y = f2bf(w.y);
        br[tid + i * 256] = o;
    }
}

// W_dec (D,H) f32 -> W_decT (H, stride WSTR) bf16 in ws; pads never read
__global__ __launch_bounds__(256) void k_transpose(const float* __restrict__ Wdec,
                                                   unsigned short* __restrict__ WdecT) {
    __shared__ float tile[32][33];
    const int h0 = blockIdx.x * 32;
    const int d0 = blockIdx.y * 32;
    const int tx = threadIdx.x & 31;
    const int ty = threadIdx.x >> 5;
#pragma unroll
    for (int r = 0; r < 4; ++r) {
        int d = ty + r * 8;
        tile[d][tx] = Wdec[(size_t)(d0 + d) * Hn + h0 + tx];
    }
    __syncthreads();
#pragma unroll
    for (int r = 0; r < 4; ++r) {
        int h = ty + r * 8;
        WdecT[(size_t)(h0 + h) * WSTR + d0 + tx] = f2bf(tile[tx][h]);
    }
}

// bf16 MFMA GEMM: 256x256 tile, BK=64, 8 waves, counted-vmcnt pipeline
// (round-12 verified)
__global__ __launch_bounds__(512, 2) void k_gemm(const unsigned short* __restrict__ Ap,
                                                 const unsigned short* __restrict__ Bp,
                                                 const float* __restrict__ lat_bias,
                                                 unsigned short* __restrict__ hout16) {
    __shared__ unsigned short AsBuf[2][256 * 64];
    __shared__ unsigned short BsBuf[2][256 * 64];
    const int tid = threadIdx.x;
    const int lane = tid & 63;
    const int w = tid >> 6;
    const int wm = w >> 2;
    const int wn = w & 3;

    const int nwg = (Bn / 256) * (Hn / 256);          // 2048, %8 == 0
    int swz = (blockIdx.x % 8) * (nwg / 8) + blockIdx.x / 8;
    int st = swz >> 6;
    int wi = swz & 63;
    int stm = st >> 3, stn = st & 7;
    const int bm = stm * 8 + (wi >> 3);
    const int bn = stn * 8 + (wi & 7);

    const size_t arow0 = (size_t)(bm * 256) * KE;
    const size_t brow0 = (size_t)(bn * 256) * KE;

    #define STAGE_TILE(kt, buf)                                                   \
        {                                                                         \
            _Pragma("unroll")                                                     \
            for (int l = 0; l < 4; ++l) {                                         \
                const int idx = l * 512 + tid;                                    \
                const int row = idx >> 3, slot = idx & 7;                         \
                const int ssl = slot ^ (row & 7);                                 \
                gload_lds16(Ap + arow0 + (size_t)row * KE + (kt) * 64 + ssl * 8,  \
                            (char*)AsBuf[buf] + idx * 16);                        \
                gload_lds16(Bp + brow0 + (size_t)row * KE + (kt) * 64 + ssl * 8,  \
                            (char*)BsBuf[buf] + idx * 16);                        \
            }                                                                     \
        }

    f32x4 acc[8][4];
#pragma unroll
    for (int i = 0; i < 8; ++i)
#pragma unroll
        for (int j = 0; j < 4; ++j) acc[i][j] = (f32x4){0.f, 0.f, 0.f, 0.f};

    constexpr int NT = KE / 64;       // 24
    STAGE_TILE(0, 0);
    STAGE_TILE(1, 1);
    asm volatile("s_waitcnt vmcnt(8)" ::: "memory");
    __builtin_amdgcn_s_barrier();
    asm volatile("" ::: "memory");

    for (int t = 0; t < NT; ++t) {
        const int buf = t & 1;
        const unsigned short* Ab = AsBuf[buf];
        const unsigned short* Bb = BsBuf[buf];
        short8 bfr[4][2];
#pragma unroll
        for (int fj = 0; fj < 4; ++fj)
#pragma unroll
            for (int kk = 0; kk < 2; ++kk) {
                const int br = wn * 64 + fj * 16 + (lane & 15);
                const int slot = (kk * 4 + (lane >> 4)) ^ (br & 7);
                bfr[fj][kk] = *(const short8*)((const char*)Bb + br * 128 + slot * 16);
            }
#pragma unroll
        for (int qm = 0; qm < 2; ++qm) {
            short8 afr[4][2];
#pragma unroll
            for (int fi = 0; fi < 4; ++fi)
#pragma unroll
                for (int kk = 0; kk < 2; ++kk) {
                    const int ar = wm * 128 + qm * 64 + fi * 16 + (lane & 15);
                    const int slot = (kk * 4 + (lane >> 4)) ^ (ar & 7);
                    afr[fi][kk] = *(const short8*)((const char*)Ab + ar * 128 + slot * 16);
                }
#pragma unroll
            for (int kk = 0; kk < 2; ++kk)
#pragma unroll
                for (int fi = 0; fi < 4; ++fi)
#pragma unroll
                    for (int fj = 0; fj < 4; ++fj)
                        acc[qm * 4 + fi][fj] = __builtin_amdgcn_mfma_f32_16x16x32_bf16(
                            afr[fi][kk], bfr[fj][kk], acc[qm * 4 + fi][fj], 0, 0, 0);
        }
        __builtin_amdgcn_s_barrier();
        asm volatile("" ::: "memory");
        if (t + 2 < NT) {
            STAGE_TILE(t + 2, buf);
            asm volatile("s_waitcnt vmcnt(8)" ::: "memory");
        } else {
            asm volatile("s_waitcnt vmcnt(0)" ::: "memory");
        }
        __builtin_amdgcn_s_barrier();
        asm volatile("" ::: "memory");
    }
    #undef STAGE_TILE

    const int col = lane & 15;
#pragma unroll
    for (int fj = 0; fj < 4; ++fj) {
        const int gn = bn * 256 + wn * 64 + fj * 16 + col;
        const float bias = lat_bias[gn];
#pragma unroll
        for (int fi8 = 0; fi8 < 8; ++fi8) {
            const int gm0 = bm * 256 + wm * 128 + fi8 * 16 + (lane >> 4) * 4;
#pragma unroll
            for (int r = 0; r < 4; ++r) {
                float vv = acc[fi8][fj][r] + bias;
                hout16[(size_t)(gm0 + r) * Hn + gn] = f2bf(fmaxf(vv, 0.f));
            }
        }
    }
}

// FUSED topsel — r18 binary bisection with ADAPTIVE midpoint schedule:
// iteration 0 probes key 2.0 (0x4000), iteration 1 probes 4.0 (0x4080) when
// the typical branch holds -> span collapses to 127 keys in 2 scans (~9 total
// vs 15). Any midpoint in (lo,hi] preserves the invariant, so the final key
// is exactly the 64th-largest for ALL inputs (schedule affects speed only).
__global__ __launch_bounds__(256) void k_topsel(const unsigned short* __restrict__ h16,
                                                const float* __restrict__ x,
                                                const float* __restrict__ Wenc,
                                                const float* __restrict__ pre_bias,
                                                const float* __restrict__ lat_bias,
                                                const double* __restrict__ muD,
                                                const double* __restrict__ rinvD,
                                                unsigned* __restrict__ counts,
                                                int* __restrict__ idx_list,
                                                float* __restrict__ val_list) {
    const int row = blockIdx.x;
    const int tid = threadIdx.x;
    const int lane = tid & 63;
    const int wid = tid >> 6;
    const unsigned short* hr16 = h16 + (size_t)row * Hn;
    const unsigned* hu = (const unsigned*)hr16;
    unsigned u[32];
#pragma unroll
    for (int j = 0; j < 32; ++j) u[j] = hu[j * 256 + tid];

    // exact 64th-largest bf16 key via atomic-free bisection
    __shared__ int wsum[4];
    __shared__ unsigned sbc;
    unsigned lo = 0, hi = 0x7FFFu;    // keys <= 0x7F7F (ReLU, finite)
    int it = 0;
    while (lo < hi) {
        unsigned mid;
        if (it == 0) mid = 0x4000u;                                     // 2.0
        else if (it == 1 && lo == 0x4000u && hi == 0x7FFFu) mid = 0x4080u; // 4.0
        else mid = (lo + hi + 1) >> 1;
        ++it;
        int c = 0;
#pragma unroll
        for (int j = 0; j < 32; ++j) {
            c += ((u[j] & 0xFFFFu) >= mid) ? 1 : 0;
            c += ((u[j] >> 16) >= mid) ? 1 : 0;
        }
#pragma unroll
        for (int o = 32; o > 0; o >>= 1) c += __shfl_down(c, o);
        if ((tid & 63) == 0) wsum[tid >> 6] = c;
        __syncthreads();
        if (tid == 0) sbc = (unsigned)(wsum[0] + wsum[1] + wsum[2] + wsum[3]);
        __syncthreads();
        if (sbc >= (unsigned)KTOP) lo = mid; else hi = mid - 1;
    }
    const float thr = bf2f((unsigned short)lo);
    const float DELTA = 0.02f;
    const float hi_t = thr + DELTA;
    const float lo_t = thr - DELTA;

    // classify from registers
    constexpr int MAXC = 128;
    __shared__ int s_g, s_c;
    __shared__ int cidx[MAXC];
    __shared__ double cvalD[MAXC];
    __shared__ float cref[MAXC];
    __shared__ unsigned char csel[MAXC];
    __shared__ unsigned long long kmask[256];
    __shared__ unsigned ccnt[256];
    __shared__ unsigned cinc[256];
    if (tid == 0) { s_g = 0; s_c = 0; }
    __syncthreads();
    int g_loc = 0;
#pragma unroll
    for (int j = 0; j < 32; ++j) {
        float v0 = bf2f((unsigned short)(u[j] & 0xFFFFu));
        float v1 = bf2f((unsigned short)(u[j] >> 16));
        const int i0 = 2 * (j * 256 + tid);
        if (v0 > hi_t) g_loc++;
        else if (v0 >= lo_t) {
            int p = atomicAdd(&s_c, 1);
            if (p < MAXC) cidx[p] = i0;
        }
        if (v1 > hi_t) g_loc++;
        else if (v1 >= lo_t) {
            int p = atomicAdd(&s_c, 1);
            if (p < MAXC) cidx[p] = i0 + 1;
        }
    }
    if (g_loc) atomicAdd(&s_g, g_loc);
    __syncthreads();
    const int ec = (s_c < MAXC) ? s_c : MAXC;

    // exact f64 recompute of band candidates, wave-parallel
    {
        const double rmu = muD[row];
        const double rin = rinvD[row];
        const float* xr = x + (size_t)row * Dn;
        for (int e = wid; e < ec; e += 4) {
            const int feat = cidx[e];
            const float* wr = Wenc + (size_t)feat * Dn;
            double acc = 0.0;
            for (int d = lane; d < Dn; d += 64) {
                double xn = ((double)xr[d] - rmu) * rin - (double)pre_bias[d];
                acc = fma(xn, (double)wr[d], acc);
            }
#pragma unroll
            for (int o = 32; o > 0; o >>= 1) acc += __shfl_down(acc, o);
            if (lane == 0) {
                double hv = acc + (double)lat_bias[feat];
                cvalD[e] = hv;
                float hf = (float)hv;
                cref[e] = hf > 0.f ? hf : 0.f;
            }
        }
    }
    __syncthreads();
    if (tid == 0) {
        const int need = KTOP - s_g;
        for (int e = 0; e < ec; ++e) csel[e] = 0;
        for (int it2 = 0; it2 < need && it2 < ec; ++it2) {
            int best = -1; double bv = -1e300; int bidx = 1 << 30;
            for (int e = 0; e < ec; ++e) {
                if (csel[e]) continue;
                if (cvalD[e] > bv || (cvalD[e] == bv && cidx[e] < bidx)) {
                    bv = cvalD[e]; best = e; bidx = cidx[e];
                }
            }
            if (best >= 0) csel[best] = 1;
        }
    }
    __syncthreads();

    // Phase A: per-chunk keep masks (re-read, L2-hot)
    for (int i = 0; i < 64; ++i) {
        const int c = wid * 64 + i;
        const int f = c * 64 + lane;
        float val = bf2f(hr16[f]);
        bool keep;
        if (val > hi_t) keep = true;
        else if (val >= lo_t) {
            keep = false;
            for (int e = 0; e < ec; ++e)
                if (cidx[e] == f) { keep = (csel[e] != 0); break; }
        } else keep = false;
        unsigned long long bm = __ballot(keep);
        if (lane == 0) { kmask[c] = bm; ccnt[c] = (unsigned)__popcll(bm); }
    }
    __syncthreads();
    // Phase B: inclusive prefix over chunk counts
    cinc[tid] = ccnt[tid];
    __syncthreads();
#pragma unroll
    for (int o = 1; o < 256; o <<= 1) {
        unsigned t = cinc[tid] + ((tid >= o) ? cinc[tid - o] : 0u);
        __syncthreads();
        cinc[tid] = t;
        __syncthreads();
    }
    if (tid == 0) {
        unsigned tot = cinc[255];
        counts[row] = tot < 128u ? tot : 128u;
    }
    __syncthreads();
    // Phase C: masked writes
    for (int i = 0; i < 64; ++i) {
        const int c = wid * 64 + i;
        unsigned long long bm = kmask[c];
        if (!bm) continue;
        bool keep = (bm >> lane) & 1ull;
        if (keep) {
            unsigned pos = (cinc[c] - ccnt[c]) +
                           (unsigned)__popcll(bm & ((1ull << lane) - 1ull));
            if (pos < 128u) {
                const int f = c * 64 + lane;
                float sv = bf2f(hr16[f]);
                if (sv >= lo_t && sv <= hi_t) {
                    for (int e = 0; e < ec; ++e)
                        if (cidx[e] == f) { sv = cref[e]; break; }
                }
                idx_list[(size_t)row * 128 + pos] = f;
                val_list[(size_t)row * 128 + pos] = sv;
            }
        }
    }
}

// FUSED hwrite + decoder (round-13 verified)
__global__ __launch_bounds__(256) void k_hwdec(const unsigned* __restrict__ counts,
                                               const int* __restrict__ idx_list,
                                               const float* __restrict__ val_list,
                                               const unsigned short* __restrict__ WdecT,
                                               const float* __restrict__ pre_bias,
                                               const float* __restrict__ muF,
                                               const float* __restrict__ stdF,
                                               float* __restrict__ outh,
                                               float* __restrict__ outr,
                                               unsigned* __restrict__ nnz_acc,
                                               double* __restrict__ sums) {
    const int row = blockIdx.x;
    const int tid = threadIdx.x;
    const unsigned cnt = counts[row];
    __shared__ int sidx[128];
    __shared__ float sval[128];
    if (tid < (int)cnt) {
        sidx[tid] = idx_list[(size_t)row * 128 + tid];
        sval[tid] = val_list[(size_t)row * 128 + tid];
    }
    float* orow = outh + (size_t)row * Hn;
    float4* orow16 = (float4*)orow;
    const float4 z = {0.f, 0.f, 0.f, 0.f};
#pragma unroll
    for (int i = 0; i < 16; ++i) orow16[tid + i * 256] = z;
    __syncthreads();
    float val = 0.f;
    if (tid < (int)cnt) { orow[sidx[tid]] = sval[tid]; val = sval[tid]; }
    float s1 = val, s2 = val * val;
    __shared__ float r1[4], r2[4];
#pragma unroll
    for (int o = 32; o > 0; o >>= 1) {
        s1 += __shfl_down(s1, o);
        s2 += __shfl_down(s2, o);
    }
    if ((tid & 63) == 0) { r1[tid >> 6] = s1; r2[tid >> 6] = s2; }
    __syncthreads();
    if (tid == 0) {
        atomicAdd(sums + 0, (double)(r1[0] + r1[1] + r1[2] + r1[3]));
        atomicAdd(sums + 1, (double)(r2[0] + r2[1] + r2[2] + r2[3]));
        atomicAdd(nnz_acc, cnt);
    }
    if (tid >= 192) return;
    float a[8] = {0.f, 0.f, 0.f, 0.f, 0.f, 0.f, 0.f, 0.f};
    float b[8] = {0.f, 0.f, 0.f, 0.f, 0.f, 0.f, 0.f, 0.f};
    const size_t toff = (size_t)tid * 8;
    unsigned j = 0;
    for (; j + 2 <= cnt; j += 2) {
        short8 w0 = *(const short8*)(WdecT + (size_t)sidx[j] * WSTR + toff);
        short8 w1 = *(const short8*)(WdecT + (size_t)sidx[j + 1] * WSTR + toff);
        const float v0 = sval[j], v1 = sval[j + 1];
#pragma unroll
        for (int i = 0; i < 8; ++i) {
            a[i] = fmaf(v0, bf2f((unsigned short)w0[i]), a[i]);
            b[i] = fmaf(v1, bf2f((unsigned short)w1[i]), b[i]);
        }
    }
    if (j < cnt) {
        short8 w0 = *(const short8*)(WdecT + (size_t)sidx[j] * WSTR + toff);
        const float v0 = sval[j];
#pragma unroll
        for (int i = 0; i < 8; ++i)
            a[i] = fmaf(v0, bf2f((unsigned short)w0[i]), a[i]);
    }
    const float m_ = muF[row], s_ = stdF[row];
    const int d0 = tid * 8;
    float o[8];
#pragma unroll
    for (int i = 0; i < 8; ++i)
        o[i] = ((a[i] + b[i]) + pre_bias[d0 + i]) * s_ + m_;
    float* rrow = outr + (size_t)row * Dn + d0;
    *(float4*)(rrow)     = *(float4*)&o[0];
    *(float4*)(rrow + 4) = *(float4*)&o[4];
}

__global__ void k_final(const unsigned* __restrict__ nnz,
                        const double* __restrict__ sums,
                        float* __restrict__ out3) {
    if (threadIdx.x == 0) {
        const double N = (double)Bn * (double)Hn;
        const double nz = (double)(*nnz);
        const double sparsity = (N - nz) / N;
        const double mean = sums[0] / N;
        double var = (sums[1] - N * mean * mean) / (N - 1.0);
        if (var < 0.0) var = 0.0;
        out3[0] = (float)sparsity;
        out3[1] = (float)mean;
        out3[2] = (float)sqrt(var);
    }
}

extern "C" void kernel_launch(void* const* d_in, const int* in_sizes, int n_in,
                              void* d_out, int out_size, void* d_ws, size_t ws_size,
                              hipStream_t stream) {
    const float* x        = (const float*)d_in[0];
    const float* Wenc     = (const float*)d_in[1];
    const float* Wdec     = (const float*)d_in[2];
    const float* pre_bias = (const float*)d_in[3];
    const float* lat_bias = (const float*)d_in[4];

    char* ws = (char*)d_ws;
    float*          muF    = (float*)(ws + MU_OFF);
    float*          stdF   = (float*)(ws + STD_OFF);
    unsigned*       counts = (unsigned*)(ws + CNT_OFF);
    unsigned*       nnz    = (unsigned*)(ws + NNZ_OFF);
    double*         sums   = (double*)(ws + SUM_OFF);
    double*         muD    = (double*)(ws + MUD_OFF);
    double*         rinvD  = (double*)(ws + RID_OFF);
    int*            idxl   = (int*)(ws + IDX_OFF);
    float*          vall   = (float*)(ws + VAL_OFF);
    unsigned short* Ap     = (unsigned short*)(ws + AP_OFF);
    unsigned short* Bp     = (unsigned short*)(ws + BP_OFF);
    unsigned short* WdecT  = (unsigned short*)(ws + WT_OFF);
    unsigned short* h16    = (unsigned short*)(ws + H16_OFF);

    float* out       = (float*)d_out;
    float* out_recon = out;
    float* out_h     = out + (size_t)Bn * Dn;
    float* out_sc    = out + (size_t)Bn * Dn + (size_t)Bn * Hn;

    hipLaunchKernelGGL(k_zero, dim3(1), dim3(64), 0, stream, nnz, sums);
    hipLaunchKernelGGL(k_rowstats, dim3(Bn), dim3(256), 0, stream,
                       x, pre_bias, muD, rinvD, muF, stdF, Ap);
    hipLaunchKernelGGL(k_splitW, dim3(Hn), dim3(256), 0, stream, Wenc, Bp);
    hipLaunchKernelGGL(k_transpose, dim3(Hn / 32, Dn / 32), dim3(256), 0, stream, Wdec, WdecT);
    hipLaunchKernelGGL(k_gemm, dim3((Bn / 256) * (Hn / 256)), dim3(512), 0, stream,
                       Ap, Bp, lat_bias, h16);
    hipLaunchKernelGGL(k_topsel, dim3(Bn), dim3(256), 0, stream,
                       h16, x, Wenc, pre_bias, lat_bias, muD, rinvD,
                       counts, idxl, vall);
    hipLaunchKernelGGL(k_hwdec, dim3(Bn), dim3(256), 0, stream,
                       counts, idxl, vall, WdecT, pre_bias, muF, stdF,
                       out_h, out_recon, nnz, sums);
    hipLaunchKernelGGL(k_final, dim3(1), dim3(64), 0, stream, nnz, sums, out_sc);
}